// Round 5
// baseline (218.096 us; speedup 1.0000x reference)
//
#include <hip/hip_runtime.h>

#define HH 64
#define WW 64
#define CC 128
#define FF 256
#define NTAP 9
#define KD 1152   // NTAP*CC
#define MTOT 32768
#define XELEMS (8 * HH * WW * CC)   // 4194304
#define XCVT_BLOCKS (XELEMS / (256 * 8))  // 2048
#define WT_BLOCKS 144               // 36864 threads, 8 k each

typedef __attribute__((ext_vector_type(8))) short bf16x8;
typedef __attribute__((ext_vector_type(4))) float floatx4;

__device__ __constant__ int c_iy[9] = {0,0,1,2,2,1,0,2,1};
__device__ __constant__ int c_ix[9] = {0,1,1,2,0,2,1,0,2};

__device__ inline unsigned short f2bf(float v) {
  union { float f; unsigned u; } c; c.f = v;
  unsigned r = (c.u + 0x7FFFu + ((c.u >> 16) & 1u)) >> 16;  // RNE
  return (unsigned short)r;
}
__device__ inline float bflo(unsigned u) {
  union { unsigned u; float f; } c; c.u = u << 16; return c.f;
}
__device__ inline float bfhi(unsigned u) {
  union { unsigned u; float f; } c; c.u = u & 0xFFFF0000u; return c.f;
}

// ---- Prep: X fp32->bf16, and W [k][f] -> Wt [f][k] bf16 (coalesced reads, 16B stores)
__global__ void prep_kernel(const float* __restrict__ X, const float* __restrict__ W,
                            unsigned short* __restrict__ Xb, unsigned short* __restrict__ Wt) {
  const int blk = blockIdx.x;
  if (blk < XCVT_BLOCKS) {                  // X convert, 8 elems/thread
    const int t = blk * 256 + threadIdx.x;
    const float4* src = (const float4*)(X + (size_t)t * 8);
    float4 a = src[0], b2 = src[1];
    bf16x8 o;
    o[0] = (short)f2bf(a.x);  o[1] = (short)f2bf(a.y);
    o[2] = (short)f2bf(a.z);  o[3] = (short)f2bf(a.w);
    o[4] = (short)f2bf(b2.x); o[5] = (short)f2bf(b2.y);
    o[6] = (short)f2bf(b2.z); o[7] = (short)f2bf(b2.w);
    *(bf16x8*)(Xb + (size_t)t * 8) = o;
  } else {                                  // W transpose: thread = (f, 8 k's)
    const int t = (blk - XCVT_BLOCKS) * 256 + threadIdx.x;  // 0..36863
    const int f = t & 255;
    const int k0 = (t >> 8) * 8;            // 0..1144
    unsigned short o[8];
#pragma unroll
    for (int i2 = 0; i2 < 8; ++i2)
      o[i2] = f2bf(W[(size_t)(k0 + i2) * FF + f]);   // lanes: consecutive f -> coalesced
    *(uint4*)(Wt + (size_t)f * KD + k0) = *(uint4*)o; // one 16B store
  }
}

// ---- Kernel A: bilinear gather/interp producer (bf16 corners) ----
__global__ __launch_bounds__(256, 4) void interp_kernel(
    const unsigned short* __restrict__ Xb, const float* __restrict__ Off,
    unsigned short* __restrict__ Mp)
{
  const int blk = blockIdx.x;            // 0..18431
  const int b   = blk & 7;
  const int bw  = blk >> 3;
  const int tid = threadIdx.x;
  const int g   = tid >> 4;
  const int c   = tid & 15;
  const unsigned item = (unsigned)bw * 16u + g;
  const unsigned pos_local = item / 9u;
  const int n = (int)(item - pos_local * 9u);
  const int y = (int)(pos_local >> 6);
  const int x = (int)(pos_local & 63u);

  float2 off2 = *(const float2*)(Off + ((size_t)(b * HH + y) * WW + x) * (2 * NTAP) + 2 * n);
  float cy = (float)(y - 1 + c_iy[n]) + off2.x;
  float cx = (float)(x - 1 + c_ix[n]) + off2.y;
  cy = fminf(fmaxf(cy, 0.f), 63.f);
  cx = fminf(fmaxf(cx, 0.f), 63.f);
  float fy0 = floorf(cy), fy1 = ceilf(cy);
  float fx0 = floorf(cx), fx1 = ceilf(cx);
  int y0 = (int)fy0, y1 = (int)fy1, x0 = (int)fx0, x1 = (int)fx1;
  float fy = cy - fy0;
  float fx = cx - fx0;

  const unsigned short* xb = Xb + (size_t)b * (HH * WW * CC);
  const uint4 q00 = *(const uint4*)(xb + (y0 * WW + x0) * CC + c * 8);
  const uint4 q10 = *(const uint4*)(xb + (y1 * WW + x0) * CC + c * 8);
  const uint4 q01 = *(const uint4*)(xb + (y0 * WW + x1) * CC + c * 8);
  const uint4 q11 = *(const uint4*)(xb + (y1 * WW + x1) * CC + c * 8);

  const unsigned u00[4] = {q00.x, q00.y, q00.z, q00.w};
  const unsigned u10[4] = {q10.x, q10.y, q10.z, q10.w};
  const unsigned u01[4] = {q01.x, q01.y, q01.z, q01.w};
  const unsigned u11[4] = {q11.x, q11.y, q11.z, q11.w};

  unsigned outw[4];
#pragma unroll
  for (int j = 0; j < 4; ++j) {
    float v00 = bflo(u00[j]), v10 = bflo(u10[j]), v01 = bflo(u01[j]), v11 = bflo(u11[j]);
    float tx = v00 + (v10 - v00) * fy;
    float tb = v01 + (v11 - v01) * fy;
    unsigned short rlo = f2bf(tx + (tb - tx) * fx);
    v00 = bfhi(u00[j]); v10 = bfhi(u10[j]); v01 = bfhi(u01[j]); v11 = bfhi(u11[j]);
    tx = v00 + (v10 - v00) * fy;
    tb = v01 + (v11 - v01) * fy;
    unsigned short rhi = f2bf(tx + (tb - tx) * fx);
    outw[j] = (unsigned)rlo | ((unsigned)rhi << 16);
  }

  unsigned short* dst = Mp + (size_t)(b * 4096 + pos_local) * KD + n * CC + c * 8;
  *(uint4*)dst = make_uint4(outw[0], outw[1], outw[2], outw[3]);
}

// ---- Kernel B: GEMM 32768x1152x256, 64Mx128F blocks, raw-barrier 2-deep pipeline ----
__global__ __launch_bounds__(256, 4) void gemm_kernel(
    const unsigned short* __restrict__ Mp, const unsigned short* __restrict__ Wt,
    const float* __restrict__ bias, float* __restrict__ Out)
{
  __shared__ unsigned short smA[64 * 64];    // 8 KB
  __shared__ unsigned short smB[128 * 64];   // 16 KB

  const int blk = blockIdx.x;         // 0..1023
  const int b   = blk & 7;            // XCD locality: batch b -> XCD b
  const int q   = blk >> 3;
  const int fb  = q & 1;              // fb pairs adjacent in launch order -> A L2 reuse
  const int i   = q >> 1;             // 0..63 M-tile within batch
  const int m0  = b * 4096 + i * 64;
  const int f0  = fb * 128;
  const int tid = threadIdx.x;
  const int wave = tid >> 6, lane = tid & 63;
  const int wf = wave * 32;           // wave covers 32 F
  const int arow = lane & 15, aq = lane >> 4;
  const int sch = tid & 7;
  const int srow = tid >> 3;          // 0..31
  const int swz = (sch ^ (srow & 7)) * 8;  // XOR-swizzled LDS chunk slot

  uint4 aR[2], bR[4];

#define LOADT(KT)                                                             \
  {                                                                           \
    const int k0 = (KT) * 64;                                                 \
    _Pragma("unroll")                                                         \
    for (int p = 0; p < 2; ++p)                                               \
      aR[p] = *(const uint4*)(Mp + (size_t)(m0 + p * 32 + srow) * KD + k0 + sch * 8); \
    _Pragma("unroll")                                                         \
    for (int p = 0; p < 4; ++p)                                               \
      bR[p] = *(const uint4*)(Wt + (size_t)(f0 + p * 32 + srow) * KD + k0 + sch * 8); \
  }

#define DSW()                                                                 \
  {                                                                           \
    _Pragma("unroll")                                                         \
    for (int p = 0; p < 2; ++p)                                               \
      *(uint4*)&smA[(p * 32 + srow) * 64 + swz] = aR[p];                      \
    _Pragma("unroll")                                                         \
    for (int p = 0; p < 4; ++p)                                               \
      *(uint4*)&smB[(p * 32 + srow) * 64 + swz] = bR[p];                      \
  }

  floatx4 acc[4][2];
#pragma unroll
  for (int mt = 0; mt < 4; ++mt)
#pragma unroll
    for (int ft = 0; ft < 2; ++ft)
      acc[mt][ft] = (floatx4){0.f, 0.f, 0.f, 0.f};

  LOADT(0)
  DSW()               // compiler inserts vm wait for aR/bR deps
  LOADT(1)            // tile 1 in flight across the barrier (no drain)
  asm volatile("s_waitcnt lgkmcnt(0)" ::: "memory");
  asm volatile("s_barrier" ::: "memory");

  for (int kt = 0; kt < 18; ++kt) {
#pragma unroll
    for (int ks = 0; ks < 2; ++ks) {
      bf16x8 afr[4], bfr[2];
      const int cidx = (((ks * 4 + aq) ^ (arow & 7)) * 8);
#pragma unroll
      for (int mt = 0; mt < 4; ++mt)
        afr[mt] = *(const bf16x8*)&smA[(mt * 16 + arow) * 64 + cidx];
#pragma unroll
      for (int ft = 0; ft < 2; ++ft)
        bfr[ft] = *(const bf16x8*)&smB[(wf + ft * 16 + arow) * 64 + cidx];
#pragma unroll
      for (int mt = 0; mt < 4; ++mt)
#pragma unroll
        for (int ft = 0; ft < 2; ++ft)
          acc[mt][ft] = __builtin_amdgcn_mfma_f32_16x16x32_bf16(afr[mt], bfr[ft], acc[mt][ft], 0, 0, 0);
    }
    // All ds_read results consumed by MFMAs (compiler lgkm-waited) before this barrier.
    asm volatile("s_barrier" ::: "memory");          // B1: safe to overwrite LDS
    if (kt < 17) DSW()                               // stage kt+1 (regs from prev iter)
    if (kt < 16) LOADT(kt + 2)                       // prefetch stays in flight past B2
    asm volatile("s_waitcnt lgkmcnt(0)" ::: "memory");
    asm volatile("s_barrier" ::: "memory");          // B2: LDS tile kt+1 visible
  }
#undef LOADT
#undef DSW

  float bv[2];
#pragma unroll
  for (int ft = 0; ft < 2; ++ft)
    bv[ft] = bias[f0 + wf + ft * 16 + arow];
#pragma unroll
  for (int mt = 0; mt < 4; ++mt) {
#pragma unroll
    for (int ft = 0; ft < 2; ++ft) {
      const int f = f0 + wf + ft * 16 + arow;
#pragma unroll
      for (int r = 0; r < 4; ++r) {
        const int m = m0 + mt * 16 + aq * 4 + r;
        Out[(size_t)m * FF + f] = acc[mt][ft][r] + bv[ft];
      }
    }
  }
}

extern "C" void kernel_launch(void* const* d_in, const int* in_sizes, int n_in,
                              void* d_out, int out_size, void* d_ws, size_t ws_size,
                              hipStream_t stream) {
  const float* X    = (const float*)d_in[0];
  const float* Off  = (const float*)d_in[1];
  const float* W    = (const float*)d_in[2];
  const float* bias = (const float*)d_in[3];
  float* Out = (float*)d_out;

  unsigned short* Wt = (unsigned short*)d_ws;                  // 294912 shorts
  unsigned short* Mp = Wt + (size_t)FF * KD;                   // 37748736 shorts
  unsigned short* Xb = Mp + (size_t)MTOT * KD;                 // 4194304 shorts

  prep_kernel<<<XCVT_BLOCKS + WT_BLOCKS, 256, 0, stream>>>(X, W, Xb, Wt);
  interp_kernel<<<(MTOT * NTAP * 16) / 256, 256, 0, stream>>>(Xb, Off, Mp);
  gemm_kernel<<<1024, 256, 0, stream>>>(Mp, Wt, bias, Out);
}

// Round 6
// 171.246 us; speedup vs baseline: 1.2736x; 1.2736x over previous
//
#include <hip/hip_runtime.h>

#define HH 64
#define WW 64
#define CC 128
#define FF 256
#define NTAP 9
#define KD 1152   // NTAP*CC
#define MTOT 32768
#define XELEMS (8 * HH * WW * CC)         // 4194304
#define XCVT_BLOCKS (XELEMS / (256 * 8))  // 2048
#define WT_BLOCKS 144                     // 36864 threads, 8 k each

typedef __attribute__((ext_vector_type(8))) short bf16x8;
typedef __attribute__((ext_vector_type(4))) float floatx4;

__device__ __constant__ int c_iy[9] = {0,0,1,2,2,1,0,2,1};
__device__ __constant__ int c_ix[9] = {0,1,1,2,0,2,1,0,2};

__device__ inline unsigned short f2bf(float v) {
  union { float f; unsigned u; } c; c.f = v;
  unsigned r = (c.u + 0x7FFFu + ((c.u >> 16) & 1u)) >> 16;  // RNE
  return (unsigned short)r;
}
__device__ inline float bflo(unsigned u) {
  union { unsigned u; float f; } c; c.u = u << 16; return c.f;
}
__device__ inline float bfhi(unsigned u) {
  union { unsigned u; float f; } c; c.u = u & 0xFFFF0000u; return c.f;
}

// ---- Prep: X fp32->bf16, and W [k][f] -> Wt [f][k] bf16 (coalesced reads, 16B stores)
__global__ void prep_kernel(const float* __restrict__ X, const float* __restrict__ W,
                            unsigned short* __restrict__ Xb, unsigned short* __restrict__ Wt) {
  const int blk = blockIdx.x;
  if (blk < XCVT_BLOCKS) {                  // X convert, 8 elems/thread
    const int t = blk * 256 + threadIdx.x;
    const float4* src = (const float4*)(X + (size_t)t * 8);
    float4 a = src[0], b2 = src[1];
    bf16x8 o;
    o[0] = (short)f2bf(a.x);  o[1] = (short)f2bf(a.y);
    o[2] = (short)f2bf(a.z);  o[3] = (short)f2bf(a.w);
    o[4] = (short)f2bf(b2.x); o[5] = (short)f2bf(b2.y);
    o[6] = (short)f2bf(b2.z); o[7] = (short)f2bf(b2.w);
    *(bf16x8*)(Xb + (size_t)t * 8) = o;
  } else {                                  // W transpose: thread = (f, 8 k's)
    const int t = (blk - XCVT_BLOCKS) * 256 + threadIdx.x;  // 0..36863
    const int f = t & 255;
    const int k0 = (t >> 8) * 8;
    unsigned short o[8];
#pragma unroll
    for (int i2 = 0; i2 < 8; ++i2)
      o[i2] = f2bf(W[(size_t)(k0 + i2) * FF + f]);   // lanes: consecutive f -> coalesced
    *(uint4*)(Wt + (size_t)f * KD + k0) = *(uint4*)o;
  }
}

// ---- Kernel A: bilinear gather/interp producer (bf16 corners) ----
__global__ __launch_bounds__(256, 4) void interp_kernel(
    const unsigned short* __restrict__ Xb, const float* __restrict__ Off,
    unsigned short* __restrict__ Mp)
{
  const int blk = blockIdx.x;            // 0..18431
  const int b   = blk & 7;
  const int bw  = blk >> 3;
  const int tid = threadIdx.x;
  const int g   = tid >> 4;
  const int c   = tid & 15;
  const unsigned item = (unsigned)bw * 16u + g;
  const unsigned pos_local = item / 9u;
  const int n = (int)(item - pos_local * 9u);
  const int y = (int)(pos_local >> 6);
  const int x = (int)(pos_local & 63u);

  float2 off2 = *(const float2*)(Off + ((size_t)(b * HH + y) * WW + x) * (2 * NTAP) + 2 * n);
  float cy = (float)(y - 1 + c_iy[n]) + off2.x;
  float cx = (float)(x - 1 + c_ix[n]) + off2.y;
  cy = fminf(fmaxf(cy, 0.f), 63.f);
  cx = fminf(fmaxf(cx, 0.f), 63.f);
  float fy0 = floorf(cy), fy1 = ceilf(cy);
  float fx0 = floorf(cx), fx1 = ceilf(cx);
  int y0 = (int)fy0, y1 = (int)fy1, x0 = (int)fx0, x1 = (int)fx1;
  float fy = cy - fy0;
  float fx = cx - fx0;

  const unsigned short* xb = Xb + (size_t)b * (HH * WW * CC);
  const uint4 q00 = *(const uint4*)(xb + (y0 * WW + x0) * CC + c * 8);
  const uint4 q10 = *(const uint4*)(xb + (y1 * WW + x0) * CC + c * 8);
  const uint4 q01 = *(const uint4*)(xb + (y0 * WW + x1) * CC + c * 8);
  const uint4 q11 = *(const uint4*)(xb + (y1 * WW + x1) * CC + c * 8);

  const unsigned u00[4] = {q00.x, q00.y, q00.z, q00.w};
  const unsigned u10[4] = {q10.x, q10.y, q10.z, q10.w};
  const unsigned u01[4] = {q01.x, q01.y, q01.z, q01.w};
  const unsigned u11[4] = {q11.x, q11.y, q11.z, q11.w};

  unsigned outw[4];
#pragma unroll
  for (int j = 0; j < 4; ++j) {
    float v00 = bflo(u00[j]), v10 = bflo(u10[j]), v01 = bflo(u01[j]), v11 = bflo(u11[j]);
    float tx = v00 + (v10 - v00) * fy;
    float tb = v01 + (v11 - v01) * fy;
    unsigned short rlo = f2bf(tx + (tb - tx) * fx);
    v00 = bfhi(u00[j]); v10 = bfhi(u10[j]); v01 = bfhi(u01[j]); v11 = bfhi(u11[j]);
    tx = v00 + (v10 - v00) * fy;
    tb = v01 + (v11 - v01) * fy;
    unsigned short rhi = f2bf(tx + (tb - tx) * fx);
    outw[j] = (unsigned)rlo | ((unsigned)rhi << 16);
  }

  unsigned short* dst = Mp + (size_t)(b * 4096 + pos_local) * KD + n * CC + c * 8;
  *(uint4*)dst = make_uint4(outw[0], outw[1], outw[2], outw[3]);
}

// ---- Kernel B: GEMM 32768x1152x256. 64M x 128F blocks, A double-buffered via
// global_load_lds (16 KB LDS), B fragments direct from L2-resident Wt. ----
__global__ __launch_bounds__(256, 4) void gemm_kernel(
    const unsigned short* __restrict__ Mp, const unsigned short* __restrict__ Wt,
    const float* __restrict__ bias, float* __restrict__ Out)
{
  __shared__ unsigned short smA[2][64 * 64];   // 8 KB per buffer

  const int blk = blockIdx.x;         // 0..1023
  const int b   = blk & 7;            // batch -> XCD locality
  const int q   = blk >> 3;           // 0..127
  const int fb  = q & 1;              // fb pairs adjacent on an XCD -> A L2 reuse
  const int i   = q >> 1;             // 0..63 M-tile within batch
  const int m0  = b * 4096 + i * 64;
  const int f0  = fb * 128;
  const int tid = threadIdx.x;
  const int wave = tid >> 6, lane = tid & 63;
  const int wm = (wave & 1) * 32;     // wave: 32 M x 64 F
  const int wf = (wave >> 1) * 64;
  const int arow = lane & 15, aq = lane >> 4;
  const int srow = tid >> 3;          // 0..31
  const int sch  = tid & 7;

  floatx4 acc[2][4];
#pragma unroll
  for (int mt = 0; mt < 2; ++mt)
#pragma unroll
    for (int ft = 0; ft < 4; ++ft)
      acc[mt][ft] = (floatx4){0.f, 0.f, 0.f, 0.f};

  // Stage A tile (64 rows x 64 k, bf16): 2 x 16B per thread, XOR chunk swizzle.
#define STAGE_A(BUF, KT)                                                            \
  {                                                                                 \
    _Pragma("unroll")                                                               \
    for (int p = 0; p < 2; ++p) {                                                   \
      int row = p * 32 + srow;                                                      \
      int chp = sch ^ (row & 7);                                                    \
      const unsigned short* gp = Mp + (size_t)(m0 + row) * KD + (KT) * 64 + chp * 8;\
      unsigned short* l = (unsigned short*)&smA[BUF][row * 64 + sch * 8];           \
      __builtin_amdgcn_global_load_lds(                                             \
          (const __attribute__((address_space(1))) unsigned int*)gp,                \
          (__attribute__((address_space(3))) unsigned int*)l, 16, 0, 0);            \
    }                                                                               \
  }

  STAGE_A(0, 0)
  __syncthreads();

  const unsigned short* wrow = Wt + (size_t)(f0 + wf + arow) * KD + aq * 8;

  for (int kt = 0; kt < 18; ++kt) {
    const int cur = kt & 1, nxt = cur ^ 1;
    if (kt + 1 < 18) STAGE_A(nxt, kt + 1)

#pragma unroll
    for (int ks = 0; ks < 2; ++ks) {
      const int koff = kt * 64 + ks * 32;
      bf16x8 bfr[4], afr[2];
#pragma unroll
      for (int ft = 0; ft < 4; ++ft)
        bfr[ft] = *(const bf16x8*)(wrow + (size_t)ft * 16 * KD + koff);
      const int slot = (((ks * 4 + aq) ^ (arow & 7)) * 8);
#pragma unroll
      for (int mt = 0; mt < 2; ++mt)
        afr[mt] = *(const bf16x8*)&smA[cur][(wm + mt * 16 + arow) * 64 + slot];
#pragma unroll
      for (int mt = 0; mt < 2; ++mt)
#pragma unroll
        for (int ft = 0; ft < 4; ++ft)
          acc[mt][ft] = __builtin_amdgcn_mfma_f32_16x16x32_bf16(afr[mt], bfr[ft], acc[mt][ft], 0, 0, 0);
    }
    __syncthreads();
  }
#undef STAGE_A

  float bv[4];
#pragma unroll
  for (int ft = 0; ft < 4; ++ft)
    bv[ft] = bias[f0 + wf + ft * 16 + arow];
#pragma unroll
  for (int mt = 0; mt < 2; ++mt) {
#pragma unroll
    for (int ft = 0; ft < 4; ++ft) {
      const int f = f0 + wf + ft * 16 + arow;
#pragma unroll
      for (int r = 0; r < 4; ++r) {
        const int m = m0 + wm + mt * 16 + aq * 4 + r;
        Out[(size_t)m * FF + f] = acc[mt][ft][r] + bv[ft];
      }
    }
  }
}

extern "C" void kernel_launch(void* const* d_in, const int* in_sizes, int n_in,
                              void* d_out, int out_size, void* d_ws, size_t ws_size,
                              hipStream_t stream) {
  const float* X    = (const float*)d_in[0];
  const float* Off  = (const float*)d_in[1];
  const float* W    = (const float*)d_in[2];
  const float* bias = (const float*)d_in[3];
  float* Out = (float*)d_out;

  unsigned short* Wt = (unsigned short*)d_ws;                  // 294912 shorts
  unsigned short* Mp = Wt + (size_t)FF * KD;                   // 37748736 shorts
  unsigned short* Xb = Mp + (size_t)MTOT * KD;                 // 4194304 shorts

  prep_kernel<<<XCVT_BLOCKS + WT_BLOCKS, 256, 0, stream>>>(X, W, Xb, Wt);
  interp_kernel<<<(MTOT * NTAP * 16) / 256, 256, 0, stream>>>(Xb, Off, Mp);
  gemm_kernel<<<1024, 256, 0, stream>>>(Mp, Wt, bias, Out);
}

// Round 7
// 123.583 us; speedup vs baseline: 1.7648x; 1.3857x over previous
//
#include <hip/hip_runtime.h>

#define HH 64
#define WW 64
#define CC 128
#define FF 256
#define NTAP 9
#define KD 1152   // NTAP*CC
#define MTOT 32768
#define XELEMS (8 * HH * WW * CC)         // 4194304
#define XCVT_BLOCKS (XELEMS / (256 * 8))  // 2048
#define WT_BLOCKS 144                     // 36864 threads, 8 k each

typedef __attribute__((ext_vector_type(8))) short bf16x8;
typedef __attribute__((ext_vector_type(4))) float floatx4;

__device__ __constant__ int c_iy[9] = {0,0,1,2,2,1,0,2,1};
__device__ __constant__ int c_ix[9] = {0,1,1,2,0,2,1,0,2};

__device__ inline unsigned short f2bf(float v) {
  union { float f; unsigned u; } c; c.f = v;
  unsigned r = (c.u + 0x7FFFu + ((c.u >> 16) & 1u)) >> 16;  // RNE
  return (unsigned short)r;
}
__device__ inline float bflo(unsigned u) {
  union { unsigned u; float f; } c; c.u = u << 16; return c.f;
}
__device__ inline float bfhi(unsigned u) {
  union { unsigned u; float f; } c; c.u = u & 0xFFFF0000u; return c.f;
}

// ---- Prep: X fp32->bf16, and W [k][f] -> Wt [f][k] bf16 (coalesced reads, 16B stores)
__global__ void prep_kernel(const float* __restrict__ X, const float* __restrict__ W,
                            unsigned short* __restrict__ Xb, unsigned short* __restrict__ Wt) {
  const int blk = blockIdx.x;
  if (blk < XCVT_BLOCKS) {                  // X convert, 8 elems/thread
    const int t = blk * 256 + threadIdx.x;
    const float4* src = (const float4*)(X + (size_t)t * 8);
    float4 a = src[0], b2 = src[1];
    bf16x8 o;
    o[0] = (short)f2bf(a.x);  o[1] = (short)f2bf(a.y);
    o[2] = (short)f2bf(a.z);  o[3] = (short)f2bf(a.w);
    o[4] = (short)f2bf(b2.x); o[5] = (short)f2bf(b2.y);
    o[6] = (short)f2bf(b2.z); o[7] = (short)f2bf(b2.w);
    *(bf16x8*)(Xb + (size_t)t * 8) = o;
  } else {                                  // W transpose: thread = (f, 8 k's)
    const int t = (blk - XCVT_BLOCKS) * 256 + threadIdx.x;  // 0..36863
    const int f = t & 255;
    const int k0 = (t >> 8) * 8;
    unsigned short o[8];
#pragma unroll
    for (int i2 = 0; i2 < 8; ++i2)
      o[i2] = f2bf(W[(size_t)(k0 + i2) * FF + f]);   // lanes: consecutive f -> coalesced
    *(uint4*)(Wt + (size_t)f * KD + k0) = *(uint4*)o;
  }
}

// ---- Kernel A: bilinear gather/interp. One 16-lane group = one position, all 9 taps.
// 9 independent taps unrolled -> deep load ILP; taps share corner cells via L1;
// the 9 stores per group tile one contiguous 2304-B Mp row.
__global__ __launch_bounds__(256, 4) void interp_kernel(
    const unsigned short* __restrict__ Xb, const float* __restrict__ Off,
    unsigned short* __restrict__ Mp)
{
  const int blk = blockIdx.x;            // 0..2047
  const int b   = blk & 7;               // batch -> XCD locality
  const int pg  = blk >> 3;              // 0..255
  const int tid = threadIdx.x;
  const int g   = tid >> 4;              // group 0..15
  const int c   = tid & 15;              // channel chunk (8 ch)
  const int pos_local = pg * 16 + g;     // 0..4095
  const int y = pos_local >> 6;
  const int x = pos_local & 63;

  const unsigned short* xb = Xb + (size_t)b * (HH * WW * CC);
  const float* offp = Off + ((size_t)(b * HH + y) * WW + x) * (2 * NTAP);
  unsigned short* dstrow = Mp + (size_t)(b * 4096 + pos_local) * KD + c * 8;

#pragma unroll
  for (int n = 0; n < NTAP; ++n) {
    float2 off2 = *(const float2*)(offp + 2 * n);   // broadcast within group
    float cy = (float)(y - 1 + c_iy[n]) + off2.x;
    float cx = (float)(x - 1 + c_ix[n]) + off2.y;
    cy = fminf(fmaxf(cy, 0.f), 63.f);
    cx = fminf(fmaxf(cx, 0.f), 63.f);
    float fy0 = floorf(cy), fy1 = ceilf(cy);
    float fx0 = floorf(cx), fx1 = ceilf(cx);
    int y0 = (int)fy0, y1 = (int)fy1, x0 = (int)fx0, x1 = (int)fx1;
    float fy = cy - fy0;
    float fx = cx - fx0;

    const uint4 q00 = *(const uint4*)(xb + (y0 * WW + x0) * CC + c * 8); // lt
    const uint4 q10 = *(const uint4*)(xb + (y1 * WW + x0) * CC + c * 8); // rt (y1,x0)
    const uint4 q01 = *(const uint4*)(xb + (y0 * WW + x1) * CC + c * 8); // lb (y0,x1)
    const uint4 q11 = *(const uint4*)(xb + (y1 * WW + x1) * CC + c * 8); // rb

    const unsigned u00[4] = {q00.x, q00.y, q00.z, q00.w};
    const unsigned u10[4] = {q10.x, q10.y, q10.z, q10.w};
    const unsigned u01[4] = {q01.x, q01.y, q01.z, q01.w};
    const unsigned u11[4] = {q11.x, q11.y, q11.z, q11.w};

    unsigned outw[4];
#pragma unroll
    for (int j = 0; j < 4; ++j) {
      float v00 = bflo(u00[j]), v10 = bflo(u10[j]), v01 = bflo(u01[j]), v11 = bflo(u11[j]);
      float tx = v00 + (v10 - v00) * fy;
      float tb = v01 + (v11 - v01) * fy;
      unsigned short rlo = f2bf(tx + (tb - tx) * fx);
      v00 = bfhi(u00[j]); v10 = bfhi(u10[j]); v01 = bfhi(u01[j]); v11 = bfhi(u11[j]);
      tx = v00 + (v10 - v00) * fy;
      tb = v01 + (v11 - v01) * fy;
      unsigned short rhi = f2bf(tx + (tb - tx) * fx);
      outw[j] = (unsigned)rlo | ((unsigned)rhi << 16);
    }
    *(uint4*)(dstrow + n * CC) = make_uint4(outw[0], outw[1], outw[2], outw[3]);
  }
}

// ---- Kernel B: GEMM 32768x1152x256. 64M x 128F blocks, grid 1024 (4 blocks/CU),
// single-buffered LDS (24 KB), A+B staged via global_load_lds w=16, XOR swizzle. ----
__global__ __launch_bounds__(256, 4) void gemm_kernel(
    const unsigned short* __restrict__ Mp, const unsigned short* __restrict__ Wt,
    const float* __restrict__ bias, float* __restrict__ Out)
{
  __shared__ unsigned short smA[64 * 64];    // 8 KB
  __shared__ unsigned short smB[128 * 64];   // 16 KB

  const int blk = blockIdx.x;         // 0..1023
  const int b   = blk & 7;            // batch -> XCD locality
  const int q   = blk >> 3;           // 0..127
  const int fb  = q & 1;              // fb pairs adjacent on an XCD -> A L2 reuse
  const int i   = q >> 1;             // 0..63 M-tile within batch
  const int m0  = b * 4096 + i * 64;
  const int f0  = fb * 128;
  const int tid = threadIdx.x;
  const int wave = tid >> 6, lane = tid & 63;
  const int wm = (wave & 1) * 32;     // wave: 32 M x 64 F
  const int wf = (wave >> 1) * 64;
  const int arow = lane & 15, aq = lane >> 4;
  const int srow = tid >> 3;          // 0..31
  const int sch  = tid & 7;

  floatx4 acc[2][4];
#pragma unroll
  for (int mt = 0; mt < 2; ++mt)
#pragma unroll
    for (int ft = 0; ft < 4; ++ft)
      acc[mt][ft] = (floatx4){0.f, 0.f, 0.f, 0.f};

  // LDS dest per lane = base + lane*16 (wave-uniform-base rule); swizzle on global side.
#define STAGE(KT)                                                                    \
  {                                                                                  \
    _Pragma("unroll")                                                                \
    for (int p = 0; p < 2; ++p) {                                                    \
      int row = p * 32 + srow;                                                       \
      int chp = sch ^ (row & 7);                                                     \
      const unsigned short* gp = Mp + (size_t)(m0 + row) * KD + (KT) * 64 + chp * 8; \
      unsigned short* l = (unsigned short*)&smA[row * 64 + sch * 8];                 \
      __builtin_amdgcn_global_load_lds(                                              \
          (const __attribute__((address_space(1))) unsigned int*)gp,                 \
          (__attribute__((address_space(3))) unsigned int*)l, 16, 0, 0);             \
    }                                                                                \
    _Pragma("unroll")                                                                \
    for (int p = 0; p < 4; ++p) {                                                    \
      int row = p * 32 + srow;                                                       \
      int chp = sch ^ (row & 7);                                                     \
      const unsigned short* gp = Wt + (size_t)(f0 + row) * KD + (KT) * 64 + chp * 8; \
      unsigned short* l = (unsigned short*)&smB[row * 64 + sch * 8];                 \
      __builtin_amdgcn_global_load_lds(                                              \
          (const __attribute__((address_space(1))) unsigned int*)gp,                 \
          (__attribute__((address_space(3))) unsigned int*)l, 16, 0, 0);             \
    }                                                                                \
  }

  STAGE(0)
  __syncthreads();

  for (int kt = 0; kt < 18; ++kt) {
#pragma unroll
    for (int ks = 0; ks < 2; ++ks) {
      bf16x8 afr[2], bfr[4];
      const int slot = (((ks * 4 + aq) ^ (arow & 7)) * 8);
#pragma unroll
      for (int mt = 0; mt < 2; ++mt)
        afr[mt] = *(const bf16x8*)&smA[(wm + mt * 16 + arow) * 64 + slot];
#pragma unroll
      for (int ft = 0; ft < 4; ++ft)
        bfr[ft] = *(const bf16x8*)&smB[(wf + ft * 16 + arow) * 64 + slot];
#pragma unroll
      for (int mt = 0; mt < 2; ++mt)
#pragma unroll
        for (int ft = 0; ft < 4; ++ft)
          acc[mt][ft] = __builtin_amdgcn_mfma_f32_16x16x32_bf16(afr[mt], bfr[ft], acc[mt][ft], 0, 0, 0);
    }
    __syncthreads();                 // all waves done reading this tile
    if (kt + 1 < 18) STAGE(kt + 1)
    __syncthreads();                 // staged tile visible
  }
#undef STAGE

  float bv[4];
#pragma unroll
  for (int ft = 0; ft < 4; ++ft)
    bv[ft] = bias[f0 + wf + ft * 16 + arow];
#pragma unroll
  for (int mt = 0; mt < 2; ++mt) {
#pragma unroll
    for (int ft = 0; ft < 4; ++ft) {
      const int f = f0 + wf + ft * 16 + arow;
#pragma unroll
      for (int r = 0; r < 4; ++r) {
        const int m = m0 + wm + mt * 16 + aq * 4 + r;
        Out[(size_t)m * FF + f] = acc[mt][ft][r] + bv[ft];
      }
    }
  }
}

extern "C" void kernel_launch(void* const* d_in, const int* in_sizes, int n_in,
                              void* d_out, int out_size, void* d_ws, size_t ws_size,
                              hipStream_t stream) {
  const float* X    = (const float*)d_in[0];
  const float* Off  = (const float*)d_in[1];
  const float* W    = (const float*)d_in[2];
  const float* bias = (const float*)d_in[3];
  float* Out = (float*)d_out;

  unsigned short* Wt = (unsigned short*)d_ws;                  // 294912 shorts
  unsigned short* Mp = Wt + (size_t)FF * KD;                   // 37748736 shorts
  unsigned short* Xb = Mp + (size_t)MTOT * KD;                 // 4194304 shorts

  prep_kernel<<<XCVT_BLOCKS + WT_BLOCKS, 256, 0, stream>>>(X, W, Xb, Wt);
  interp_kernel<<<2048, 256, 0, stream>>>(Xb, Off, Mp);
  gemm_kernel<<<1024, 256, 0, stream>>>(Mp, Wt, bias, Out);
}